// Round 12
// baseline (120.775 us; speedup 1.0000x reference)
//
#include <hip/hip_runtime.h>

// ContrastiveLoss: loss = sum_n [ log(sum_j exp(2*<ne_n,ne_j>)) - 2*<ne_n,nt_n> ] / (2N)
// N=8192, D=512.
// R11: ASYMMETRIC OPERAND PATHS. A-panel (64 KB, contiguous in pair-shuffled
//      neb) staged to LDS once per block via global_load_lds w16 (ONE barrier
//      total); B streamed from global with depth-2 register pipeline (free:
//      64 KB LDS caps residency at 2 blocks/CU, so up to 256 VGPR/wave costs
//      nothing). K-loop: 4 B-loads/pair (global, vmcnt) + 4 ds_read_b128/pair
//      (A, lgkm ~40cyc) + 32 MFMA. k_norm/k_final/layout/XCD schedule
//      unchanged from R10 (verified, absmax 0.0).

typedef __attribute__((ext_vector_type(4))) float floatx4;
typedef __attribute__((ext_vector_type(2))) long long2v;

#define N 8192
#define D 512
#define NPAIR 8          // 8 pairs x 64 k = 512
#define NT 64            // 128-row tiles per dim

__device__ __forceinline__ void gload_lds16(const void* g, void* l) {
    __builtin_amdgcn_global_load_lds(
        (const __attribute__((address_space(1))) void*)g,
        (__attribute__((address_space(3))) void*)l, 16, 0, 0);
}

// Per-XCD segment tables: 5 segments each = [diag36, off64, off64, off64, half32].
__device__ __constant__ unsigned char seg_ga[8][5] = {
    {0,0,0,0,0},{1,1,1,1,0},{2,2,2,2,2},{3,3,3,3,2},
    {4,0,0,0,4},{5,1,1,1,4},{6,2,3,4,6},{7,4,5,5,6}};
__device__ __constant__ unsigned char seg_gb[8][5] = {
    {0,2,3,4,1},{1,2,3,4,1},{2,5,6,7,3},{3,5,6,7,3},
    {4,5,6,7,5},{5,5,6,7,5},{6,4,4,6,7},{7,7,6,7,7}};

__global__ __launch_bounds__(256) void k_norm(const float* __restrict__ emb,
                                              const float* __restrict__ tgt,
                                              unsigned char* __restrict__ neb,
                                              float* __restrict__ pos,
                                              float* __restrict__ out) {
    if (blockIdx.x == 0 && threadIdx.x == 0) *out = 0.0f;   // replaces memset dispatch
    int wave = threadIdx.x >> 6;
    int lane = threadIdx.x & 63;
    int row  = blockIdx.x * 4 + wave;          // one wave per row; lane holds k=lane*8..+8
    const float4* e4 = (const float4*)(emb + (size_t)row * D) + lane * 2;
    const float4* t4 = (const float4*)(tgt + (size_t)row * D) + lane * 2;
    float4 e0 = e4[0], e1 = e4[1];
    float4 t0 = t4[0], t1 = t4[1];
    float ee = e0.x*e0.x + e0.y*e0.y + e0.z*e0.z + e0.w*e0.w
             + e1.x*e1.x + e1.y*e1.y + e1.z*e1.z + e1.w*e1.w;
    float tt = t0.x*t0.x + t0.y*t0.y + t0.z*t0.z + t0.w*t0.w
             + t1.x*t1.x + t1.y*t1.y + t1.z*t1.z + t1.w*t1.w;
    float et = e0.x*t0.x + e0.y*t0.y + e0.z*t0.z + e0.w*t0.w
             + e1.x*t1.x + e1.y*t1.y + e1.z*t1.z + e1.w*t1.w;
    #pragma unroll
    for (int off = 1; off < 64; off <<= 1) {
        ee += __shfl_xor(ee, off);
        tt += __shfl_xor(tt, off);
        et += __shfl_xor(et, off);
    }
    float se = fmaxf(sqrtf(ee), 1e-12f);
    float st = fmaxf(sqrtf(tt), 1e-12f);
    if (lane == 0) pos[row] = et / (se * st);
    float inv = 1.0f / se;
    // pack 8 e4m3 bytes (k ascending) via HW RNE converts
    int w0 = __builtin_amdgcn_cvt_pk_fp8_f32(e0.x * inv, e0.y * inv, 0, false);
    w0     = __builtin_amdgcn_cvt_pk_fp8_f32(e0.z * inv, e0.w * inv, w0, true);
    int w1 = __builtin_amdgcn_cvt_pk_fp8_f32(e1.x * inv, e1.y * inv, 0, false);
    w1     = __builtin_amdgcn_cvt_pk_fp8_f32(e1.z * inv, e1.w * inv, w1, true);
    uint2 pk; pk.x = (unsigned)w0; pk.y = (unsigned)w1;
    // pair-interleaved shuffled store (see R7 derivation)
    size_t u2idx = (size_t)(row >> 4) * 1024
                 + (size_t)(lane >> 3) * 128
                 + (size_t)((lane & 3) * 16 + (row & 15)) * 2
                 + ((lane >> 2) & 1);
    ((uint2*)neb)[u2idx] = pk;
}

__global__ __launch_bounds__(256, 2) void k_gemm(const unsigned char* __restrict__ neb,
                                                 float* __restrict__ partial) {
    __shared__ unsigned char sA[65536];       // full A panel: 128 rows x 512 k fp8

    // XCD-partitioned decode: x = XCD stream, s = sequence within stream
    const int x = (int)(blockIdx.x & 7);
    int s = (int)(blockIdx.x >> 3);          // 0..259
    int seg, u;
    if (s < 36)       { seg = 0; u = s; }
    else if (s < 100) { seg = 1; u = s - 36; }
    else if (s < 164) { seg = 2; u = s - 100; }
    else if (s < 228) { seg = 3; u = s - 164; }
    else              { seg = 4; u = s - 228 + ((x & 1) ? 32 : 0); }
    const int ga = seg_ga[x][seg], gb = seg_gb[x][seg];
    int bi, bj;
    if (seg == 0) {                           // diag supertile: tri decode in 8x8
        int di = 0;
        while (u >= 8 - di) { u -= 8 - di; ++di; }
        bi = ga * 8 + di; bj = gb * 8 + di + u;
    } else {
        bi = ga * 8 + (u >> 3); bj = gb * 8 + (u & 7);
    }

    const int tid  = threadIdx.x;
    const int i0   = bi * 128, j0 = bj * 128;
    const int wave = tid >> 6, lane = tid & 63;
    const int wrow = wave >> 1, wcol = wave & 1;   // 2x2 waves, each 64x64
    const int m16  = lane & 15, quad = lane >> 4;

    // ---- stage A panel (64 KB, contiguous: row-blocks bi*8 .. bi*8+8) ----
    // wave w stages bytes [w*16384, +16384) in 16 x 1 KB DMA issues.
    {
        const char* gA = (const char*)neb + (size_t)(bi * 8) * 8192 + wave * 16384 + lane * 16;
        char* lA = (char*)sA + wave * 16384;              // wave-uniform base (+lane*16 by HW)
        #pragma unroll
        for (int it = 0; it < 16; ++it)
            gload_lds16(gA + it * 1024, lA + it * 1024);
    }

    // B fragment base (global, pair-shuffled): frag t at +t*8192, pair p at +p*1024
    const char* baseB = (const char*)neb + (size_t)(j0 / 16 + wcol * 4) * 8192 + lane * 16;
    // A fragment LDS offsets: frag t, pair p -> (wrow*4+t)*8192 + p*1024 + lane*16
    const unsigned aoff = (unsigned)(wrow * 4) * 8192u + (unsigned)lane * 16u;

    floatx4 zero = {0.f, 0.f, 0.f, 0.f};
    floatx4 acc[4][4];
    #pragma unroll
    for (int a = 0; a < 4; ++a)
        #pragma unroll
        for (int b = 0; b < 4; ++b) acc[a][b] = zero;

    // B: depth-2 register pipeline (3 buffers); A: depth-1 from LDS (2 buffers)
    long2v bv[3][4], av[2][4];
    #pragma unroll
    for (int t = 0; t < 4; ++t) bv[0][t] = *(const long2v*)(baseB + t * 8192);
    #pragma unroll
    for (int t = 0; t < 4; ++t) bv[1][t] = *(const long2v*)(baseB + t * 8192 + 1024);

    __syncthreads();                          // the ONLY barrier: A panel ready
    #pragma unroll
    for (int t = 0; t < 4; ++t) av[0][t] = *(const long2v*)(sA + aoff + t * 8192);

    #pragma unroll
    for (int p = 0; p < NPAIR; ++p) {
        const int cur = p % 3;
        if (p + 2 < NPAIR) {                  // B prefetch, depth 2
            const int nx = (p + 2) % 3;
            const int ko = (p + 2) * 1024;
            #pragma unroll
            for (int t = 0; t < 4; ++t) bv[nx][t] = *(const long2v*)(baseB + t * 8192 + ko);
        }
        const int ac = p & 1;
        if (p + 1 < NPAIR) {                  // A prefetch from LDS, depth 1
            const int ko = (p + 1) * 1024;
            #pragma unroll
            for (int t = 0; t < 4; ++t) av[ac ^ 1][t] = *(const long2v*)(sA + aoff + t * 8192 + ko);
        }
        #pragma unroll
        for (int ti = 0; ti < 4; ++ti)
            #pragma unroll
            for (int tj = 0; tj < 4; ++tj)
                acc[ti][tj] = __builtin_amdgcn_mfma_f32_16x16x32_fp8_fp8(av[ac][ti][0], bv[cur][tj][0], acc[ti][tj], 0, 0, 0);
        #pragma unroll
        for (int ti = 0; ti < 4; ++ti)
            #pragma unroll
            for (int tj = 0; tj < 4; ++tj)
                acc[ti][tj] = __builtin_amdgcn_mfma_f32_16x16x32_fp8_fp8(av[ac][ti][1], bv[cur][tj][1], acc[ti][tj], 0, 0, 0);
    }

    // row-sums: exp(2*c) summed over this block's 128 cols -> slot bj*2+wcol
    const int prow = bj * 2 + wcol;
    #pragma unroll
    for (int ti = 0; ti < 4; ++ti) {
        #pragma unroll
        for (int r = 0; r < 4; ++r) {
            float ss = 0.f;
            #pragma unroll
            for (int tj = 0; tj < 4; ++tj) ss += __expf(2.0f * acc[ti][tj][r]);
            #pragma unroll
            for (int off = 1; off < 16; off <<= 1) ss += __shfl_xor(ss, off);
            if (m16 == 0) {
                int rowg = i0 + wrow * 64 + ti * 16 + quad * 4 + r;
                partial[(size_t)prow * N + rowg] = ss;
            }
        }
    }
    // col-sums (symmetry: = row-sums of skipped tile (bj,bi)) -> slot bi*2+wrow
    if (bi < bj) {
        const int pcol = bi * 2 + wrow;
        #pragma unroll
        for (int tj = 0; tj < 4; ++tj) {
            float ss = 0.f;
            #pragma unroll
            for (int ti = 0; ti < 4; ++ti) {
                #pragma unroll
                for (int r = 0; r < 4; ++r) ss += __expf(2.0f * acc[ti][tj][r]);
            }
            ss += __shfl_xor(ss, 16);
            ss += __shfl_xor(ss, 32);
            if (quad == 0) {
                int colg = j0 + wcol * 64 + tj * 16 + m16;
                partial[(size_t)pcol * N + colg] = ss;
            }
        }
    }
}

__global__ __launch_bounds__(256) void k_final(const float* __restrict__ partial,
                                               const float* __restrict__ pos,
                                               float* __restrict__ out) {
    int tid = threadIdx.x;
    int row = blockIdx.x * 64 + (tid >> 2);
    int sub = tid & 3;
    float S = 0.f;
    #pragma unroll
    for (int i = 0; i < 32; ++i) S += partial[(size_t)(sub + i * 4) * N + row];
    S += __shfl_xor(S, 1);
    S += __shfl_xor(S, 2);
    float val = (sub == 0) ? (logf(S) - 2.0f * pos[row]) : 0.0f;
    #pragma unroll
    for (int off = 4; off < 64; off <<= 1) val += __shfl_xor(val, off);
    if ((tid & 63) == 0) atomicAdd(out, val * (1.0f / (2.0f * N)));
}

extern "C" void kernel_launch(void* const* d_in, const int* in_sizes, int n_in,
                              void* d_out, int out_size, void* d_ws, size_t ws_size,
                              hipStream_t stream) {
    const float* emb = (const float*)d_in[0];
    const float* tgt = (const float*)d_in[1];
    unsigned char* neb = (unsigned char*)d_ws;                                   // 4 MB fp8 ne (pair-shuffled)
    float* pos     = (float*)((char*)d_ws + (size_t)N * D);                      // 32 KB
    float* partial = (float*)((char*)d_ws + (size_t)N * D + (size_t)N * 4);      // 4 MB
    float* out = (float*)d_out;

    k_norm<<<N / 4, 256, 0, stream>>>(emb, tgt, neb, pos, out);
    k_gemm<<<NT * (NT + 1) / 2, 256, 0, stream>>>(neb, partial);
    k_final<<<N / 64, 256, 0, stream>>>(partial, pos, out);
}

// Round 13
// 113.422 us; speedup vs baseline: 1.0648x; 1.0648x over previous
//
#include <hip/hip_runtime.h>

// ContrastiveLoss: loss = sum_n [ log(sum_j exp(2*<ne_n,ne_j>)) - 2*<ne_n,nt_n> ] / (2N)
// N=8192, D=512.
// R12 = R10 (best verified: 115.5 us total, absmax 0.0). Final configuration:
//   k_norm : fused normalize + fp8 e4m3 convert + pair-interleaved operand-
//            tiled store (1 KB per (16-row x 64-k) pair-tile, offset lane*16)
//   k_gemm : barrier-free K-loop, fragments loaded straight global->VGPR as
//            single coalesced dwordx4 (two k-chunks per load), depth-1 pair
//            prefetch, symmetric triangle only (row-sums + col-sums),
//            XCD-partitioned schedule, fp32 exp/sum epilogue
//   k_final: partial-sum reduce + log - 2*pos + scalar atomic
// Structural ceiling at HIP level (R1-R11 counter evidence): gemm ~40 us vs
// 17 us MFMA floor -- residual is L2-latency exposure that register-depth
// (R8), tile-fatness (R9), occupancy (R10), and LDS paths (R1-R3, R11) all
// failed to close; finer vmcnt pipelining requires hand-asm (m131-m141).

typedef __attribute__((ext_vector_type(4))) float floatx4;
typedef __attribute__((ext_vector_type(2))) long long2v;

#define N 8192
#define D 512
#define NPAIR 8          // 8 pairs x 64 k = 512
#define NT 64            // 128-row tiles per dim

// Per-XCD segment tables: 5 segments each = [diag36, off64, off64, off64, half32].
__device__ __constant__ unsigned char seg_ga[8][5] = {
    {0,0,0,0,0},{1,1,1,1,0},{2,2,2,2,2},{3,3,3,3,2},
    {4,0,0,0,4},{5,1,1,1,4},{6,2,3,4,6},{7,4,5,5,6}};
__device__ __constant__ unsigned char seg_gb[8][5] = {
    {0,2,3,4,1},{1,2,3,4,1},{2,5,6,7,3},{3,5,6,7,3},
    {4,5,6,7,5},{5,5,6,7,5},{6,4,4,6,7},{7,7,6,7,7}};

__global__ __launch_bounds__(256) void k_norm(const float* __restrict__ emb,
                                              const float* __restrict__ tgt,
                                              unsigned char* __restrict__ neb,
                                              float* __restrict__ pos,
                                              float* __restrict__ out) {
    if (blockIdx.x == 0 && threadIdx.x == 0) *out = 0.0f;   // replaces memset dispatch
    int wave = threadIdx.x >> 6;
    int lane = threadIdx.x & 63;
    int row  = blockIdx.x * 4 + wave;          // one wave per row; lane holds k=lane*8..+8
    const float4* e4 = (const float4*)(emb + (size_t)row * D) + lane * 2;
    const float4* t4 = (const float4*)(tgt + (size_t)row * D) + lane * 2;
    float4 e0 = e4[0], e1 = e4[1];
    float4 t0 = t4[0], t1 = t4[1];
    float ee = e0.x*e0.x + e0.y*e0.y + e0.z*e0.z + e0.w*e0.w
             + e1.x*e1.x + e1.y*e1.y + e1.z*e1.z + e1.w*e1.w;
    float tt = t0.x*t0.x + t0.y*t0.y + t0.z*t0.z + t0.w*t0.w
             + t1.x*t1.x + t1.y*t1.y + t1.z*t1.z + t1.w*t1.w;
    float et = e0.x*t0.x + e0.y*t0.y + e0.z*t0.z + e0.w*t0.w
             + e1.x*t1.x + e1.y*t1.y + e1.z*t1.z + e1.w*t1.w;
    #pragma unroll
    for (int off = 1; off < 64; off <<= 1) {
        ee += __shfl_xor(ee, off);
        tt += __shfl_xor(tt, off);
        et += __shfl_xor(et, off);
    }
    float se = fmaxf(sqrtf(ee), 1e-12f);
    float st = fmaxf(sqrtf(tt), 1e-12f);
    if (lane == 0) pos[row] = et / (se * st);
    float inv = 1.0f / se;
    // pack 8 e4m3 bytes (k ascending) via HW RNE converts
    int w0 = __builtin_amdgcn_cvt_pk_fp8_f32(e0.x * inv, e0.y * inv, 0, false);
    w0     = __builtin_amdgcn_cvt_pk_fp8_f32(e0.z * inv, e0.w * inv, w0, true);
    int w1 = __builtin_amdgcn_cvt_pk_fp8_f32(e1.x * inv, e1.y * inv, 0, false);
    w1     = __builtin_amdgcn_cvt_pk_fp8_f32(e1.z * inv, e1.w * inv, w1, true);
    uint2 pk; pk.x = (unsigned)w0; pk.y = (unsigned)w1;
    // pair-interleaved shuffled store:
    // rb = row>>4 (8 KB block), pair p = lane>>3 (1 KB), chunk parity
    // par = (lane>>2)&1, q' = lane&3, m = row&15.
    // uint2 slot = p*128 + (q'*16+m)*2 + par  ->  k_gemm lane (q,m) reads
    // 16 B at p*1024 + (q*16+m)*16 = [chunk 2p | chunk 2p+1] fragment data.
    size_t u2idx = (size_t)(row >> 4) * 1024
                 + (size_t)(lane >> 3) * 128
                 + (size_t)((lane & 3) * 16 + (row & 15)) * 2
                 + ((lane >> 2) & 1);
    ((uint2*)neb)[u2idx] = pk;
}

__global__ __launch_bounds__(256, 4) void k_gemm(const unsigned char* __restrict__ neb,
                                                 float* __restrict__ partial) {
    // XCD-partitioned decode: x = XCD stream, s = sequence within stream
    const int x = (int)(blockIdx.x & 7);
    int s = (int)(blockIdx.x >> 3);          // 0..259
    int seg, u;
    if (s < 36)       { seg = 0; u = s; }
    else if (s < 100) { seg = 1; u = s - 36; }
    else if (s < 164) { seg = 2; u = s - 100; }
    else if (s < 228) { seg = 3; u = s - 164; }
    else              { seg = 4; u = s - 228 + ((x & 1) ? 32 : 0); }
    const int ga = seg_ga[x][seg], gb = seg_gb[x][seg];
    int bi, bj;
    if (seg == 0) {                           // diag supertile: tri decode in 8x8
        int di = 0;
        while (u >= 8 - di) { u -= 8 - di; ++di; }
        bi = ga * 8 + di; bj = gb * 8 + di + u;
    } else {
        bi = ga * 8 + (u >> 3); bj = gb * 8 + (u & 7);
    }

    const int tid  = threadIdx.x;
    const int i0   = bi * 128, j0 = bj * 128;
    const int wave = tid >> 6, lane = tid & 63;
    const int wrow = wave >> 1, wcol = wave & 1;   // 2x2 waves, each 64x64
    const int m16  = lane & 15, quad = lane >> 4;

    // fragment bases: 16-row block spans 8 KB (8 pairs x 1 KB); frag t at
    // +t*8192, pair p at +p*1024; lane offset lane*16 (contiguous 1 KB/wave).
    const char* baseA = (const char*)neb + (size_t)(i0 / 16 + wrow * 4) * 8192 + lane * 16;
    const char* baseB = (const char*)neb + (size_t)(j0 / 16 + wcol * 4) * 8192 + lane * 16;

    floatx4 zero = {0.f, 0.f, 0.f, 0.f};
    floatx4 acc[4][4];
    #pragma unroll
    for (int a = 0; a < 4; ++a)
        #pragma unroll
        for (int b = 0; b < 4; ++b) acc[a][b] = zero;

    long2v ca[4], cb[4], na[4], nb[4];
    #pragma unroll
    for (int t = 0; t < 4; ++t) {
        ca[t] = *(const long2v*)(baseA + t * 8192);
        cb[t] = *(const long2v*)(baseB + t * 8192);
    }

    #pragma unroll
    for (int p = 0; p < NPAIR; ++p) {
        if (p + 1 < NPAIR) {
            const int ko = (p + 1) * 1024;
            #pragma unroll
            for (int t = 0; t < 4; ++t) {
                na[t] = *(const long2v*)(baseA + t * 8192 + ko);
                nb[t] = *(const long2v*)(baseB + t * 8192 + ko);
            }
        }
        #pragma unroll
        for (int ti = 0; ti < 4; ++ti)
            #pragma unroll
            for (int tj = 0; tj < 4; ++tj)
                acc[ti][tj] = __builtin_amdgcn_mfma_f32_16x16x32_fp8_fp8(ca[ti][0], cb[tj][0], acc[ti][tj], 0, 0, 0);
        #pragma unroll
        for (int ti = 0; ti < 4; ++ti)
            #pragma unroll
            for (int tj = 0; tj < 4; ++tj)
                acc[ti][tj] = __builtin_amdgcn_mfma_f32_16x16x32_fp8_fp8(ca[ti][1], cb[tj][1], acc[ti][tj], 0, 0, 0);
        #pragma unroll
        for (int t = 0; t < 4; ++t) { ca[t] = na[t]; cb[t] = nb[t]; }
    }

    // row-sums: exp(2*c) summed over this block's 128 cols -> slot bj*2+wcol
    const int prow = bj * 2 + wcol;
    #pragma unroll
    for (int ti = 0; ti < 4; ++ti) {
        #pragma unroll
        for (int r = 0; r < 4; ++r) {
            float ss = 0.f;
            #pragma unroll
            for (int tj = 0; tj < 4; ++tj) ss += __expf(2.0f * acc[ti][tj][r]);
            #pragma unroll
            for (int off = 1; off < 16; off <<= 1) ss += __shfl_xor(ss, off);
            if (m16 == 0) {
                int rowg = i0 + wrow * 64 + ti * 16 + quad * 4 + r;
                partial[(size_t)prow * N + rowg] = ss;
            }
        }
    }
    // col-sums (symmetry: = row-sums of skipped tile (bj,bi)) -> slot bi*2+wrow
    if (bi < bj) {
        const int pcol = bi * 2 + wrow;
        #pragma unroll
        for (int tj = 0; tj < 4; ++tj) {
            float ss = 0.f;
            #pragma unroll
            for (int ti = 0; ti < 4; ++ti) {
                #pragma unroll
                for (int r = 0; r < 4; ++r) ss += __expf(2.0f * acc[ti][tj][r]);
            }
            ss += __shfl_xor(ss, 16);
            ss += __shfl_xor(ss, 32);
            if (quad == 0) {
                int colg = j0 + wcol * 64 + tj * 16 + m16;
                partial[(size_t)pcol * N + colg] = ss;
            }
        }
    }
}

__global__ __launch_bounds__(256) void k_final(const float* __restrict__ partial,
                                               const float* __restrict__ pos,
                                               float* __restrict__ out) {
    int tid = threadIdx.x;
    int row = blockIdx.x * 64 + (tid >> 2);
    int sub = tid & 3;
    float S = 0.f;
    #pragma unroll
    for (int i = 0; i < 32; ++i) S += partial[(size_t)(sub + i * 4) * N + row];
    S += __shfl_xor(S, 1);
    S += __shfl_xor(S, 2);
    float val = (sub == 0) ? (logf(S) - 2.0f * pos[row]) : 0.0f;
    #pragma unroll
    for (int off = 4; off < 64; off <<= 1) val += __shfl_xor(val, off);
    if ((tid & 63) == 0) atomicAdd(out, val * (1.0f / (2.0f * N)));
}

extern "C" void kernel_launch(void* const* d_in, const int* in_sizes, int n_in,
                              void* d_out, int out_size, void* d_ws, size_t ws_size,
                              hipStream_t stream) {
    const float* emb = (const float*)d_in[0];
    const float* tgt = (const float*)d_in[1];
    unsigned char* neb = (unsigned char*)d_ws;                                   // 4 MB fp8 ne (pair-shuffled)
    float* pos     = (float*)((char*)d_ws + (size_t)N * D);                      // 32 KB
    float* partial = (float*)((char*)d_ws + (size_t)N * D + (size_t)N * 4);      // 4 MB
    float* out = (float*)d_out;

    k_norm<<<N / 4, 256, 0, stream>>>(emb, tgt, neb, pos, out);
    k_gemm<<<NT * (NT + 1) / 2, 256, 0, stream>>>(neb, partial);
    k_final<<<N / 64, 256, 0, stream>>>(partial, pos, out);
}